// Round 1
// baseline (869.480 us; speedup 1.0000x reference)
//
#include <hip/hip_runtime.h>

#define NB 16
#define NT 128
#define NC 64
#define NU 128
#define UNFOLDS 6
#define LTC_EPS 1e-8f
#define LOG2E 1.44269504088896340736f

__global__ __launch_bounds__(512, 2)
void ltc_kernel(const float* __restrict__ x,
                const float* __restrict__ h0,
                const float* __restrict__ gleak,
                const float* __restrict__ vleak,
                const float* __restrict__ cm,
                const float* __restrict__ sigma,
                const float* __restrict__ mu,
                const float* __restrict__ w,
                const float* __restrict__ erev,
                const float* __restrict__ ssigma,
                const float* __restrict__ smu,
                const float* __restrict__ sw,
                const float* __restrict__ serev,
                const float* __restrict__ iw,
                const float* __restrict__ ib,
                const float* __restrict__ ow,
                const float* __restrict__ ob,
                float* __restrict__ out)
{
    __shared__ __align__(16) float xt_all[NT * NC];   // 32 KB, input-affine applied
    __shared__ __align__(16) float v_lds[NU];
    __shared__ __align__(16) float2 red[512];
    __shared__ __align__(16) float2 red_s[512];

    const int tid = threadIdx.x;
    const int b   = blockIdx.x;
    const int j   = tid & (NU - 1);   // post-unit
    const int k   = tid >> 7;         // pre-chunk 0..3

    // ---- persistent transformed recurrent params (registers) ----
    float rA[32], rB[32], rW[32];
#pragma unroll
    for (int c = 0; c < 32; ++c) {
        int i = k * 32 + c;
        float sg = sigma[i * NU + j];
        float m  = mu[i * NU + j];
        float wp = log1pf(expf(w[i * NU + j]));   // softplus
        float er = erev[i * NU + j];
        float a  = -sg * LOG2E;
        rA[c] = a;
        rB[c] = -a * m;          // = sg*log2e*mu
        rW[c] = wp * er;         // signed weight; |rW| = wp
    }
    // ---- persistent transformed sensory params (registers) ----
    float sA[16], sB[16], sWr[16];
#pragma unroll
    for (int c = 0; c < 16; ++c) {
        int i = k * 16 + c;
        float sg = ssigma[i * NU + j];
        float m  = smu[i * NU + j];
        float wp = log1pf(expf(sw[i * NU + j]));
        float er = serev[i * NU + j];
        float a  = -sg * LOG2E;
        sA[c]  = a;
        sB[c]  = -a * m;
        sWr[c] = wp * er;
    }

    // ---- per-j scalars (only meaningful for tid < NU) ----
    float cmt = 0.f, gl = 0.f, glv = 0.f, owj = 0.f, obj = 0.f, vj = 0.f;
    if (tid < NU) {
        cmt = 6.0f * log1pf(expf(cm[tid]));   // softplus(cm) * ODE_UNFOLDS
        gl  = log1pf(expf(gleak[tid]));
        glv = gl * vleak[tid];
        owj = ow[tid];
        obj = ob[tid];
        vj  = h0[b * NU + tid];
        v_lds[tid] = vj;
    }

    // ---- stage x with input affine ----
#pragma unroll
    for (int r = 0; r < (NT * NC) / 512; ++r) {
        int idx = r * 512 + tid;
        int c   = idx & (NC - 1);
        xt_all[idx] = x[b * NT * NC + idx] * iw[c] + ib[c];
    }
    __syncthreads();

    for (int t = 0; t < NT; ++t) {
        // -------- sensory synapses (once per step) --------
        {
            const float* xt = &xt_all[t * NC + k * 16];
            float np0 = 0.f, np1 = 0.f, dp0 = 0.f, dp1 = 0.f;
#pragma unroll
            for (int c = 0; c < 16; ++c) {
                float tt = fmaf(sA[c], xt[c], sB[c]);
                float e  = __builtin_amdgcn_exp2f(tt);
                float r  = __builtin_amdgcn_rcpf(1.0f + e);
                if (c & 1) { np1 = fmaf(sWr[c], r, np1); dp1 = fmaf(fabsf(sWr[c]), r, dp1); }
                else       { np0 = fmaf(sWr[c], r, np0); dp0 = fmaf(fabsf(sWr[c]), r, dp0); }
            }
            red_s[tid] = make_float2(np0 + np1, dp0 + dp1);
        }
        __syncthreads();
        float snum = 0.f, sden = 0.f;
        if (tid < NU) {
            float2 p0 = red_s[tid],          p1 = red_s[NU + tid];
            float2 p2 = red_s[2 * NU + tid], p3 = red_s[3 * NU + tid];
            snum = (p0.x + p1.x) + (p2.x + p3.x);
            sden = (p0.y + p1.y) + (p2.y + p3.y);
        }

        // -------- ODE unfolds --------
        for (int u = 0; u < UNFOLDS; ++u) {
            float vi[32];
#pragma unroll
            for (int q = 0; q < 8; ++q) {
                float4 vv = *(const float4*)&v_lds[k * 32 + q * 4];
                vi[q * 4 + 0] = vv.x; vi[q * 4 + 1] = vv.y;
                vi[q * 4 + 2] = vv.z; vi[q * 4 + 3] = vv.w;
            }
            float np0 = 0.f, np1 = 0.f, dp0 = 0.f, dp1 = 0.f;
#pragma unroll
            for (int c = 0; c < 32; ++c) {
                float tt = fmaf(rA[c], vi[c], rB[c]);
                float e  = __builtin_amdgcn_exp2f(tt);
                float r  = __builtin_amdgcn_rcpf(1.0f + e);
                if (c & 1) { np1 = fmaf(rW[c], r, np1); dp1 = fmaf(fabsf(rW[c]), r, dp1); }
                else       { np0 = fmaf(rW[c], r, np0); dp0 = fmaf(fabsf(rW[c]), r, dp0); }
            }
            red[tid] = make_float2(np0 + np1, dp0 + dp1);
            __syncthreads();
            if (tid < NU) {
                float2 p0 = red[tid],          p1 = red[NU + tid];
                float2 p2 = red[2 * NU + tid], p3 = red[3 * NU + tid];
                float wn = (p0.x + p1.x) + (p2.x + p3.x) + snum;
                float wd = (p0.y + p1.y) + (p2.y + p3.y) + sden;
                float numf = fmaf(cmt, vj, glv) + wn;
                float denf = cmt + gl + wd + LTC_EPS;
                vj = numf / denf;
                v_lds[tid] = vj;
            }
            __syncthreads();
        }

        if (tid < NU) {
            out[(b * NT + t) * NU + tid] = fmaf(vj, owj, obj);
        }
    }
    if (tid < NU) {
        out[NB * NT * NU + b * NU + tid] = vj;   // h_final
    }
}

extern "C" void kernel_launch(void* const* d_in, const int* in_sizes, int n_in,
                              void* d_out, int out_size, void* d_ws, size_t ws_size,
                              hipStream_t stream) {
    const float* x      = (const float*)d_in[0];
    const float* h0     = (const float*)d_in[1];
    const float* gleak  = (const float*)d_in[2];
    const float* vleak  = (const float*)d_in[3];
    const float* cm     = (const float*)d_in[4];
    const float* sigma  = (const float*)d_in[5];
    const float* mu     = (const float*)d_in[6];
    const float* w      = (const float*)d_in[7];
    const float* erev   = (const float*)d_in[8];
    const float* ssig   = (const float*)d_in[9];
    const float* smu    = (const float*)d_in[10];
    const float* sw     = (const float*)d_in[11];
    const float* serev  = (const float*)d_in[12];
    const float* iw     = (const float*)d_in[13];
    const float* ibv    = (const float*)d_in[14];
    const float* ow     = (const float*)d_in[15];
    const float* ob     = (const float*)d_in[16];
    float* out = (float*)d_out;

    ltc_kernel<<<NB, 512, 0, stream>>>(x, h0, gleak, vleak, cm, sigma, mu, w, erev,
                                       ssig, smu, sw, serev, iw, ibv, ow, ob, out);
}

// Round 2
// 853.744 us; speedup vs baseline: 1.0184x; 1.0184x over previous
//
#include <hip/hip_runtime.h>

#define NB 16
#define NT 128
#define NC 64
#define NU 128
#define UNFOLDS 6
#define LTC_EPS 1e-8f
#define LOG2E 1.44269504088896340736f
#define LN2   0.69314718055994530942f

__device__ __forceinline__ float fast_softplus(float x) {
    // softplus(x) = ln2 * log2(1 + 2^(x*log2e)); inputs here are <= ~1.0, no overflow
    return LN2 * __builtin_amdgcn_logf(1.0f + __builtin_amdgcn_exp2f(x * LOG2E));
}

template<int CTRL>
__device__ __forceinline__ float qperm(float x) {
    return __int_as_float(__builtin_amdgcn_update_dpp(
        0, __float_as_int(x), CTRL, 0xF, 0xF, true));
}
// butterfly sum over lane quads (lanes 4q..4q+3); all 4 lanes get the total
__device__ __forceinline__ float quad_sum(float x) {
    x += qperm<0xB1>(x);   // quad_perm [1,0,3,2] : xor 1
    x += qperm<0x4E>(x);   // quad_perm [2,3,0,1] : xor 2
    return x;
}

// ---------------- Kernel 1: sensory precompute (fully parallel) ----------------
// sens[b,t,j] = (sum_c sw_pos*sig(ssig*(xt-smu))*serev, sum_c sw_pos*sig(...))
__global__ __launch_bounds__(128)
void ltc_sens_kernel(const float* __restrict__ x,
                     const float* __restrict__ ssigma,
                     const float* __restrict__ smu,
                     const float* __restrict__ sw,
                     const float* __restrict__ serev,
                     const float* __restrict__ iw,
                     const float* __restrict__ ib,
                     float2* __restrict__ sens)
{
    __shared__ float xt[NC];
    const int blk = blockIdx.x;
    const int b = blk >> 7;          // / NT
    const int t = blk & (NT - 1);    // % NT
    const int j = threadIdx.x;
    if (j < NC) xt[j] = fmaf(x[(b * NT + t) * NC + j], iw[j], ib[j]);
    __syncthreads();

    float n0 = 0.f, n1 = 0.f, d0 = 0.f, d1 = 0.f;
#pragma unroll 8
    for (int c = 0; c < NC; ++c) {
        const int idx = c * NU + j;
        float sg = ssigma[idx];
        float m  = smu[idx];
        float wp = fast_softplus(sw[idx]);
        float er = serev[idx];
        float tt = (m - xt[c]) * (sg * LOG2E);          // -> sigmoid via 2^tt
        float e  = __builtin_amdgcn_exp2f(tt);
        float r  = __builtin_amdgcn_rcpf(1.0f + e);
        float wr = wp * r;
        if (c & 1) { n1 = fmaf(wr, er, n1); d1 += wr; }
        else       { n0 = fmaf(wr, er, n0); d0 += wr; }
    }
    sens[(b * NT + t) * NU + j] = make_float2(n0 + n1, d0 + d1);
}

// ---------------- Kernel 2: sequential scan, quad layout ----------------
template<bool USE_WS>
__global__ __launch_bounds__(512, 2)
void ltc_seq_kernel(const float* __restrict__ x,
                    const float* __restrict__ h0,
                    const float* __restrict__ gleak,
                    const float* __restrict__ vleak,
                    const float* __restrict__ cm,
                    const float* __restrict__ sigma,
                    const float* __restrict__ mu,
                    const float* __restrict__ w,
                    const float* __restrict__ erev,
                    const float* __restrict__ ssigma,
                    const float* __restrict__ smu,
                    const float* __restrict__ sw,
                    const float* __restrict__ serev,
                    const float* __restrict__ iw,
                    const float* __restrict__ ibv,
                    const float* __restrict__ ow,
                    const float* __restrict__ ob,
                    const float2* __restrict__ sens,
                    float* __restrict__ out)
{
    __shared__ __align__(16) float v_lds[2][NU];
    __shared__ __align__(16) float xt_all[USE_WS ? 4 : NT * NC];

    const int tid = threadIdx.x;
    const int b   = blockIdx.x;
    const int j   = tid >> 2;   // post-unit, quad-shared
    const int k   = tid & 3;    // pre-unit chunk 0..3 (32 each)

    // persistent transformed recurrent params (registers, 96 VGPR)
    float rA[32], rB[32], rW[32];
#pragma unroll
    for (int c = 0; c < 32; ++c) {
        const int idx = (k * 32 + c) * NU + j;
        float sg = sigma[idx];
        float m  = mu[idx];
        float wp = fast_softplus(w[idx]);
        float er = erev[idx];
        float a  = -sg * LOG2E;
        rA[c] = a;
        rB[c] = -a * m;
        rW[c] = wp * er;        // signed weight; |rW| = wp
    }

    float sA[16], sB[16], sWr[16];
    if (!USE_WS) {
#pragma unroll
        for (int c = 0; c < 16; ++c) {
            const int idx = (k * 16 + c) * NU + j;
            float sg = ssigma[idx];
            float m  = smu[idx];
            float wp = fast_softplus(sw[idx]);
            float er = serev[idx];
            float a  = -sg * LOG2E;
            sA[c]  = a;
            sB[c]  = -a * m;
            sWr[c] = wp * er;
        }
#pragma unroll
        for (int r = 0; r < (NT * NC) / 512; ++r) {
            int idx = r * 512 + tid;
            int cc  = idx & (NC - 1);
            xt_all[idx] = fmaf(x[b * NT * NC + idx], iw[cc], ibv[cc]);
        }
    }

    const float cmt = 6.0f * fast_softplus(cm[j]);   // softplus(cm)*ODE_UNFOLDS
    const float gl  = fast_softplus(gleak[j]);
    const float glv = gl * vleak[j];
    const float owj = ow[j];
    const float obj = ob[j];
    float vj = h0[b * NU + j];
    if (k == 0) v_lds[0][j] = vj;
    __syncthreads();

    int p = 0;
    float2 s_cur = make_float2(0.f, 0.f);
    if (USE_WS) s_cur = sens[b * NT * NU + j];

    for (int t = 0; t < NT; ++t) {
        float snum, sden;
        float2 s_next = s_cur;
        if (USE_WS) {
            snum = s_cur.x; sden = s_cur.y;
            const int tn = (t + 1 < NT) ? (t + 1) : t;
            s_next = sens[(b * NT + tn) * NU + j];   // prefetch, hidden by unfolds
        } else {
            const float* xt = &xt_all[t * NC + k * 16];
            float n0 = 0.f, n1 = 0.f, d0 = 0.f, d1 = 0.f;
#pragma unroll
            for (int c = 0; c < 16; ++c) {
                float tt = fmaf(sA[c], xt[c], sB[c]);
                float e  = __builtin_amdgcn_exp2f(tt);
                float r  = __builtin_amdgcn_rcpf(1.0f + e);
                if (c & 1) { n1 = fmaf(sWr[c], r, n1); d1 = fmaf(fabsf(sWr[c]), r, d1); }
                else       { n0 = fmaf(sWr[c], r, n0); d0 = fmaf(fabsf(sWr[c]), r, d0); }
            }
            snum = quad_sum(n0 + n1);
            sden = quad_sum(d0 + d1);
        }

#pragma unroll
        for (int u = 0; u < UNFOLDS; ++u) {
            float vi[32];
#pragma unroll
            for (int q = 0; q < 8; ++q) {
                const float4 vv = *(const float4*)&v_lds[p][k * 32 + q * 4];
                vi[q * 4 + 0] = vv.x; vi[q * 4 + 1] = vv.y;
                vi[q * 4 + 2] = vv.z; vi[q * 4 + 3] = vv.w;
            }
            float n0 = 0.f, n1 = 0.f, d0 = 0.f, d1 = 0.f;
#pragma unroll
            for (int c = 0; c < 32; ++c) {
                float tt = fmaf(rA[c], vi[c], rB[c]);
                float e  = __builtin_amdgcn_exp2f(tt);
                float r  = __builtin_amdgcn_rcpf(1.0f + e);
                if (c & 1) { n1 = fmaf(rW[c], r, n1); d1 = fmaf(fabsf(rW[c]), r, d1); }
                else       { n0 = fmaf(rW[c], r, n0); d0 = fmaf(fabsf(rW[c]), r, d0); }
            }
            const float wn = quad_sum(n0 + n1) + snum;
            const float wd = quad_sum(d0 + d1) + sden;
            const float numf = fmaf(cmt, vj, glv) + wn;
            const float denf = cmt + gl + wd + LTC_EPS;
            vj = numf / denf;                       // all 4 lanes redundantly
            if (k == 0) v_lds[p ^ 1][j] = vj;
            __syncthreads();                        // single barrier per unfold
            p ^= 1;
        }

        if (k == 0) out[(b * NT + t) * NU + j] = fmaf(vj, owj, obj);
        s_cur = s_next;
    }
    if (k == 0) out[NB * NT * NU + b * NU + j] = vj;   // h_final
}

extern "C" void kernel_launch(void* const* d_in, const int* in_sizes, int n_in,
                              void* d_out, int out_size, void* d_ws, size_t ws_size,
                              hipStream_t stream) {
    const float* x      = (const float*)d_in[0];
    const float* h0     = (const float*)d_in[1];
    const float* gleak  = (const float*)d_in[2];
    const float* vleak  = (const float*)d_in[3];
    const float* cm     = (const float*)d_in[4];
    const float* sigma  = (const float*)d_in[5];
    const float* mu     = (const float*)d_in[6];
    const float* w      = (const float*)d_in[7];
    const float* erev   = (const float*)d_in[8];
    const float* ssig   = (const float*)d_in[9];
    const float* smu    = (const float*)d_in[10];
    const float* sw     = (const float*)d_in[11];
    const float* serev  = (const float*)d_in[12];
    const float* iw     = (const float*)d_in[13];
    const float* ibv    = (const float*)d_in[14];
    const float* ow     = (const float*)d_in[15];
    const float* ob     = (const float*)d_in[16];
    float* out = (float*)d_out;

    const size_t sens_bytes = (size_t)NB * NT * NU * sizeof(float2);
    if (ws_size >= sens_bytes) {
        float2* sens = (float2*)d_ws;
        ltc_sens_kernel<<<NB * NT, 128, 0, stream>>>(x, ssig, smu, sw, serev, iw, ibv, sens);
        ltc_seq_kernel<true><<<NB, 512, 0, stream>>>(
            x, h0, gleak, vleak, cm, sigma, mu, w, erev,
            ssig, smu, sw, serev, iw, ibv, ow, ob, (const float2*)sens, out);
    } else {
        ltc_seq_kernel<false><<<NB, 512, 0, stream>>>(
            x, h0, gleak, vleak, cm, sigma, mu, w, erev,
            ssig, smu, sw, serev, iw, ibv, ow, ob, nullptr, out);
    }
}

// Round 3
// 824.495 us; speedup vs baseline: 1.0546x; 1.0355x over previous
//
#include <hip/hip_runtime.h>

#define NB 16
#define NT 128
#define NC 64
#define NU 128
#define UNFOLDS 6
#define LTC_EPS 1e-8f
#define LOG2E 1.44269504088896340736f
#define LN2   0.69314718055994530942f

__device__ __forceinline__ float fast_softplus(float x) {
    // softplus(x) = ln2 * log2(1 + 2^(x*log2e)); inputs here are <= ~1.0, no overflow
    return LN2 * __builtin_amdgcn_logf(1.0f + __builtin_amdgcn_exp2f(x * LOG2E));
}

template<int CTRL>
__device__ __forceinline__ float qperm(float x) {
    return __int_as_float(__builtin_amdgcn_update_dpp(
        0, __float_as_int(x), CTRL, 0xF, 0xF, true));
}
// butterfly sum over lane quads (lanes 4q..4q+3); all 4 lanes get the total
__device__ __forceinline__ float quad_sum(float x) {
    x += qperm<0xB1>(x);   // quad_perm [1,0,3,2] : xor 1
    x += qperm<0x4E>(x);   // quad_perm [2,3,0,1] : xor 2
    return x;
}

// ---------------- Kernel 1: sensory precompute (fully parallel) ----------------
__global__ __launch_bounds__(128)
void ltc_sens_kernel(const float* __restrict__ x,
                     const float* __restrict__ ssigma,
                     const float* __restrict__ smu,
                     const float* __restrict__ sw,
                     const float* __restrict__ serev,
                     const float* __restrict__ iw,
                     const float* __restrict__ ib,
                     float2* __restrict__ sens)
{
    __shared__ float xt[NC];
    const int blk = blockIdx.x;
    const int b = blk >> 7;          // / NT
    const int t = blk & (NT - 1);    // % NT
    const int j = threadIdx.x;
    if (j < NC) xt[j] = fmaf(x[(b * NT + t) * NC + j], iw[j], ib[j]);
    __syncthreads();

    float n0 = 0.f, n1 = 0.f, d0 = 0.f, d1 = 0.f;
#pragma unroll 8
    for (int c = 0; c < NC; ++c) {
        const int idx = c * NU + j;
        float sg = ssigma[idx];
        float m  = smu[idx];
        float wp = fast_softplus(sw[idx]);
        float er = serev[idx];
        float tt = (m - xt[c]) * (sg * LOG2E);
        float e  = __builtin_amdgcn_exp2f(tt);
        float r  = __builtin_amdgcn_rcpf(1.0f + e);
        float wr = wp * r;
        if (c & 1) { n1 = fmaf(wr, er, n1); d1 += wr; }
        else       { n0 = fmaf(wr, er, n0); d0 += wr; }
    }
    sens[(b * NT + t) * NU + j] = make_float2(n0 + n1, d0 + d1);
}

// ---------------- Kernel 2: sequential scan, quad layout ----------------
__global__ __launch_bounds__(512, 2)
void ltc_seq_kernel(const float* __restrict__ h0,
                    const float* __restrict__ gleak,
                    const float* __restrict__ vleak,
                    const float* __restrict__ cm,
                    const float* __restrict__ sigma,
                    const float* __restrict__ mu,
                    const float* __restrict__ w,
                    const float* __restrict__ erev,
                    const float* __restrict__ ow,
                    const float* __restrict__ ob,
                    const float2* __restrict__ sens,
                    float* __restrict__ out)
{
    __shared__ __align__(16) float v_lds[2][NU];

    const int tid = threadIdx.x;
    const int b   = blockIdx.x;
    const int j   = tid >> 2;   // post-unit, quad-shared
    const int k   = tid & 3;    // pre-unit chunk 0..3 (32 each)

    // persistent transformed recurrent params; slot c=4q+i holds pre-row
    // k*32 + g*4 + i with g=(q+2k)&7  (rotation -> conflict-free v reads)
    float rA[32], rB[32], rW[32];
#pragma unroll
    for (int q = 0; q < 8; ++q) {
        const int g = (q + 2 * k) & 7;
#pragma unroll
        for (int i = 0; i < 4; ++i) {
            const int c   = q * 4 + i;
            const int idx = ((k << 5) + (g << 2) + i) * NU + j;
            float sg = sigma[idx];
            float m  = mu[idx];
            float wp = fast_softplus(w[idx]);
            float er = erev[idx];
            float a  = -sg * LOG2E;
            rA[c] = a;
            rB[c] = -a * m;
            rW[c] = wp * er;        // signed weight; |rW| = wp
        }
    }
    // pin in registers: prevents rematerialization (compiler treats each value
    // as asm-defined, so it cannot re-derive it from global loads in the loop)
#pragma unroll
    for (int c = 0; c < 32; ++c) {
        asm volatile("" : "+v"(rA[c]));
        asm volatile("" : "+v"(rB[c]));
        asm volatile("" : "+v"(rW[c]));
    }

    const float cmt = 6.0f * fast_softplus(cm[j]);   // softplus(cm)*ODE_UNFOLDS
    const float gl  = fast_softplus(gleak[j]);
    const float glv = gl * vleak[j];
    const float owj = ow[j];
    const float obj = ob[j];
    float vj = h0[b * NU + j];
    if (k == 0) v_lds[0][j] = vj;
    __syncthreads();

    int p = 0;
    float2 s_cur = sens[b * NT * NU + j];

    for (int t = 0; t < NT; ++t) {
        const float snum = s_cur.x;
        const float sden = s_cur.y;
        const int tn = (t + 1 < NT) ? (t + 1) : t;
        const float2 s_next = sens[(b * NT + tn) * NU + j];  // prefetch under unfolds

#pragma unroll
        for (int u = 0; u < UNFOLDS; ++u) {
            float4 vvq[8];
#pragma unroll
            for (int q = 0; q < 8; ++q) {
                const int g = (q + 2 * k) & 7;
                vvq[q] = *(const float4*)&v_lds[p][(k << 5) + (g << 2)];
            }
            float n0 = 0.f, n1 = 0.f, d0 = 0.f, d1 = 0.f;
#pragma unroll
            for (int q = 0; q < 8; ++q) {
                const float vv[4] = { vvq[q].x, vvq[q].y, vvq[q].z, vvq[q].w };
#pragma unroll
                for (int i = 0; i < 4; ++i) {
                    const int c = q * 4 + i;
                    float tt = fmaf(rA[c], vv[i], rB[c]);
                    float e  = __builtin_amdgcn_exp2f(tt);
                    float r  = __builtin_amdgcn_rcpf(1.0f + e);
                    if (i & 1) { n1 = fmaf(rW[c], r, n1); d1 = fmaf(fabsf(rW[c]), r, d1); }
                    else       { n0 = fmaf(rW[c], r, n0); d0 = fmaf(fabsf(rW[c]), r, d0); }
                }
            }
            const float wn = quad_sum(n0 + n1) + snum;
            const float wd = quad_sum(d0 + d1) + sden;
            const float numf = fmaf(cmt, vj, glv) + wn;
            const float denf = cmt + gl + wd + LTC_EPS;
            vj = numf * __builtin_amdgcn_rcpf(denf);   // all 4 lanes redundantly
            if (k == 0) v_lds[p ^ 1][j] = vj;
            __syncthreads();                           // single barrier per unfold
            p ^= 1;
        }

        if (k == 0) out[(b * NT + t) * NU + j] = fmaf(vj, owj, obj);
        s_cur = s_next;
    }
    if (k == 0) out[NB * NT * NU + b * NU + j] = vj;   // h_final
}

extern "C" void kernel_launch(void* const* d_in, const int* in_sizes, int n_in,
                              void* d_out, int out_size, void* d_ws, size_t ws_size,
                              hipStream_t stream) {
    const float* x      = (const float*)d_in[0];
    const float* h0     = (const float*)d_in[1];
    const float* gleak  = (const float*)d_in[2];
    const float* vleak  = (const float*)d_in[3];
    const float* cm     = (const float*)d_in[4];
    const float* sigma  = (const float*)d_in[5];
    const float* mu     = (const float*)d_in[6];
    const float* w      = (const float*)d_in[7];
    const float* erev   = (const float*)d_in[8];
    const float* ssig   = (const float*)d_in[9];
    const float* smu    = (const float*)d_in[10];
    const float* sw     = (const float*)d_in[11];
    const float* serev  = (const float*)d_in[12];
    const float* iw     = (const float*)d_in[13];
    const float* ibv    = (const float*)d_in[14];
    const float* ow     = (const float*)d_in[15];
    const float* ob     = (const float*)d_in[16];
    float* out = (float*)d_out;

    float2* sens = (float2*)d_ws;   // 2 MB, guaranteed by harness ws sizing
    ltc_sens_kernel<<<NB * NT, 128, 0, stream>>>(x, ssig, smu, sw, serev, iw, ibv, sens);
    ltc_seq_kernel<<<NB, 512, 0, stream>>>(h0, gleak, vleak, cm, sigma, mu, w, erev,
                                           ow, ob, (const float2*)sens, out);
}

// Round 5
// 764.608 us; speedup vs baseline: 1.1372x; 1.0783x over previous
//
#include <hip/hip_runtime.h>

#define NB 16
#define NT 128
#define NC 64
#define NU 128
#define UNFOLDS 6
#define LTC_EPS 1e-8f
#define LOG2E 1.44269504088896340736f
#define LN2   0.69314718055994530942f

typedef float f32x2 __attribute__((ext_vector_type(2)));

__device__ __forceinline__ float fast_softplus(float x) {
    return LN2 * __builtin_amdgcn_logf(1.0f + __builtin_amdgcn_exp2f(x * LOG2E));
}

template<int CTRL>
__device__ __forceinline__ float qperm(float x) {
    return __int_as_float(__builtin_amdgcn_update_dpp(
        0, __float_as_int(x), CTRL, 0xF, 0xF, true));
}
// sum over the 8 lanes of a k-group (lanes 8g..8g+7); all 8 get the total
__device__ __forceinline__ float sum8(float x) {
    x += qperm<0xB1>(x);    // quad_perm [1,0,3,2] : xor 1
    x += qperm<0x4E>(x);    // quad_perm [2,3,0,1] : xor 2
    // xor 4 across quads: ds_swizzle BitMode offset = (4<<10)|0x1F = 0x101F
    x += __int_as_float(__builtin_amdgcn_ds_swizzle(__float_as_int(x), 0x101F));
    return x;
}

// ---------------- Kernel 1: sensory precompute (fully parallel) ----------------
__global__ __launch_bounds__(128)
void ltc_sens_kernel(const float* __restrict__ x,
                     const float* __restrict__ ssigma,
                     const float* __restrict__ smu,
                     const float* __restrict__ sw,
                     const float* __restrict__ serev,
                     const float* __restrict__ iw,
                     const float* __restrict__ ib,
                     float2* __restrict__ sens)
{
    __shared__ float xt[NC];
    const int blk = blockIdx.x;
    const int b = blk >> 7;
    const int t = blk & (NT - 1);
    const int j = threadIdx.x;
    if (j < NC) xt[j] = fmaf(x[(b * NT + t) * NC + j], iw[j], ib[j]);
    __syncthreads();

    float n0 = 0.f, n1 = 0.f, d0 = 0.f, d1 = 0.f;
#pragma unroll 8
    for (int c = 0; c < NC; ++c) {
        const int idx = c * NU + j;
        float sg = ssigma[idx];
        float m  = smu[idx];
        float wp = fast_softplus(sw[idx]);
        float er = serev[idx];
        float tt = (m - xt[c]) * (sg * LOG2E);
        float e  = __builtin_amdgcn_exp2f(tt);
        float r  = __builtin_amdgcn_rcpf(1.0f + e);
        float wr = wp * r;
        if (c & 1) { n1 = fmaf(wr, er, n1); d1 += wr; }
        else       { n0 = fmaf(wr, er, n0); d0 += wr; }
    }
    sens[(b * NT + t) * NU + j] = make_float2(n0 + n1, d0 + d1);
}

// ---------------- Kernel 2: sequential scan, 8 lanes per post-unit ----------------
__global__ __launch_bounds__(1024, 4)
void ltc_seq_kernel(const float* __restrict__ h0,
                    const float* __restrict__ gleak,
                    const float* __restrict__ vleak,
                    const float* __restrict__ cm,
                    const float* __restrict__ sigma,
                    const float* __restrict__ mu,
                    const float* __restrict__ w,
                    const float* __restrict__ erev,
                    const float* __restrict__ ow,
                    const float* __restrict__ ob,
                    const float2* __restrict__ sens,
                    float* __restrict__ out)
{
    __shared__ __align__(16) float v_lds[2][NU];

    const int tid = threadIdx.x;
    const int b   = blockIdx.x;
    const int j   = tid >> 3;   // post-unit (128)
    const int k   = tid & 7;    // pre-chunk (8 x 16 rows)

    // Transformed params, 2 pre-rows per slot. Slot q covers pre-rows
    // i0 = k*16 + 2g, i0+1 with g=(q+k)&7 (bank-conflict-free v reads:
    // even k -> even bank pairs, odd k -> odd; same addr across j-groups
    // broadcasts).
    f32x2 rA2[8], rB2[8], rW2[8], aW2[8];
#pragma unroll
    for (int q = 0; q < 8; ++q) {
        const int g   = (q + k) & 7;
        const int i0  = (k << 4) + (g << 1);
        const int id0 = i0 * NU + j;
        const int id1 = id0 + NU;
        const float sg0 = sigma[id0], sg1 = sigma[id1];
        const float m0  = mu[id0],    m1  = mu[id1];
        const float wp0 = fast_softplus(w[id0]), wp1 = fast_softplus(w[id1]);
        const float er0 = erev[id0],  er1 = erev[id1];
        f32x2 a;  a.x = -sg0 * LOG2E;  a.y = -sg1 * LOG2E;
        f32x2 bb; bb.x = -a.x * m0;    bb.y = -a.y * m1;
        f32x2 ww; ww.x = wp0 * er0;    ww.y = wp1 * er1;
        f32x2 aw; aw.x = wp0;          aw.y = wp1;       // |w| (er = ±1)
        rA2[q] = a; rB2[q] = bb; rW2[q] = ww; aW2[q] = aw;
    }
#pragma unroll
    for (int q = 0; q < 8; ++q) {
        asm volatile("" : "+v"(rA2[q]));
        asm volatile("" : "+v"(rB2[q]));
        asm volatile("" : "+v"(rW2[q]));
        asm volatile("" : "+v"(aW2[q]));
    }

    const float cmt    = 6.0f * fast_softplus(cm[j]);
    const float gl     = fast_softplus(gleak[j]);
    const float glv    = gl * vleak[j];
    const float cmt_gl = cmt + gl + LTC_EPS;
    const float owj    = ow[j];
    const float obj    = ob[j];
    float vj = h0[b * NU + j];
    if (k == 0) v_lds[0][j] = vj;
    __syncthreads();

    int p = 0;
    float2 s_cur = sens[b * NT * NU + j];

    for (int t = 0; t < NT; ++t) {
        const float snum = s_cur.x;
        const float sden = s_cur.y;
        const int tn = (t + 1 < NT) ? (t + 1) : t;
        const float2 s_next = sens[(b * NT + tn) * NU + j];   // prefetch under unfolds

#pragma unroll
        for (int u = 0; u < UNFOLDS; ++u) {
            f32x2 n2 = {0.f, 0.f};
            f32x2 d2 = {0.f, 0.f};
#pragma unroll
            for (int q = 0; q < 8; ++q) {
                const int g = (q + k) & 7;
                const f32x2 v2 = *(const f32x2*)&v_lds[p][(k << 4) + (g << 1)];
                f32x2 t2 = rA2[q] * v2 + rB2[q];        // packed fma (compiler)
                f32x2 e2;
                e2.x = __builtin_amdgcn_exp2f(t2.x);
                e2.y = __builtin_amdgcn_exp2f(t2.y);
                f32x2 u2 = e2 + (f32x2){1.0f, 1.0f};    // packed add
                f32x2 r2;
                r2.x = __builtin_amdgcn_rcpf(u2.x);
                r2.y = __builtin_amdgcn_rcpf(u2.y);
                n2 = rW2[q] * r2 + n2;                  // packed fma
                d2 = aW2[q] * r2 + d2;                  // packed fma
            }
            const float wn = sum8(n2.x + n2.y) + snum;
            const float wd = sum8(d2.x + d2.y) + sden;
            const float numf = fmaf(cmt, vj, glv) + wn;
            const float denf = cmt_gl + wd;
            vj = numf * __builtin_amdgcn_rcpf(denf);    // redundant in 8 lanes
            if (k == 0) v_lds[p ^ 1][j] = vj;
            __syncthreads();                            // one barrier per unfold
            p ^= 1;
        }

        if (k == 0) out[(b * NT + t) * NU + j] = fmaf(vj, owj, obj);
        s_cur = s_next;
    }
    if (k == 0) out[NB * NT * NU + b * NU + j] = vj;    // h_final
}

extern "C" void kernel_launch(void* const* d_in, const int* in_sizes, int n_in,
                              void* d_out, int out_size, void* d_ws, size_t ws_size,
                              hipStream_t stream) {
    const float* x      = (const float*)d_in[0];
    const float* h0     = (const float*)d_in[1];
    const float* gleak  = (const float*)d_in[2];
    const float* vleak  = (const float*)d_in[3];
    const float* cm     = (const float*)d_in[4];
    const float* sigma  = (const float*)d_in[5];
    const float* mu     = (const float*)d_in[6];
    const float* w      = (const float*)d_in[7];
    const float* erev   = (const float*)d_in[8];
    const float* ssig   = (const float*)d_in[9];
    const float* smu    = (const float*)d_in[10];
    const float* sw     = (const float*)d_in[11];
    const float* serev  = (const float*)d_in[12];
    const float* iw     = (const float*)d_in[13];
    const float* ibv    = (const float*)d_in[14];
    const float* ow     = (const float*)d_in[15];
    const float* ob     = (const float*)d_in[16];
    float* out = (float*)d_out;

    float2* sens = (float2*)d_ws;   // 2 MB scratch
    ltc_sens_kernel<<<NB * NT, 128, 0, stream>>>(x, ssig, smu, sw, serev, iw, ibv, sens);
    ltc_seq_kernel<<<NB, 1024, 0, stream>>>(h0, gleak, vleak, cm, sigma, mu, w, erev,
                                            ow, ob, (const float2*)sens, out);
}